// Round 3
// baseline (472.206 us; speedup 1.0000x reference)
//
#include <hip/hip_runtime.h>
#include <hip/hip_fp16.h>
#include <stdint.h>

#define O_FEAT 4096
#define I_FEAT 4096
#define M_DIM  2048
#define K_DIM  4096

typedef __attribute__((ext_vector_type(8))) short short8;   // 8 x bf16 (4 VGPRs)
typedef __attribute__((ext_vector_type(4))) float floatx4;  // MFMA accumulator

__device__ __forceinline__ uint16_t f32_to_bf16(float f) {
    uint32_t u = __builtin_bit_cast(uint32_t, f);
    u = (u + 0x7FFFu + ((u >> 16) & 1u)) >> 16;   // round-to-nearest-even
    return (uint16_t)u;
}
__device__ __forceinline__ float bf16_to_f32(uint16_t h) {
    uint32_t u = ((uint32_t)h) << 16;
    return __builtin_bit_cast(float, u);
}

// ---------------------------------------------------------------------------
// Kernel 1: dequant int4 -> bf16 W.
// Handles BOTH possible deliveries of base_packed:
//   uint8 mode: buffer is the raw packed bytes (words are random 32-bit)
//   int32 mode: harness widened each byte to an int32 (every word < 256)
// Wave-uniform probe of the first 64 words disambiguates (deterministic
// per dataset -> same work every call, graph-safe).
// ---------------------------------------------------------------------------
__global__ __launch_bounds__(256) void dequant_kernel(
        const void*  __restrict__ packed,
        const float* __restrict__ scales,
        uint16_t*    __restrict__ W) {
    const int lane = threadIdx.x & 63;
    uint32_t probe = ((const uint32_t*)packed)[lane];
    const bool int32mode = (__ballot(probe >= 256u) == 0ull);

    int idx = blockIdx.x * 256 + threadIdx.x;       // 2,097,152 threads
    float s = scales[idx >> 9];                     // 512 byte-quads per row

    uint32_t bytes4;                                // 4 packed bytes
    if (int32mode) {
        uint4 w = ((const uint4*)packed)[idx];      // 4 int32, each 0..255
        bytes4 = (w.x & 0xFFu) | ((w.y & 0xFFu) << 8) |
                 ((w.z & 0xFFu) << 16) | ((w.w & 0xFFu) << 24);
    } else {
        bytes4 = ((const uint32_t*)packed)[idx];
    }

    uint16_t o[8];
#pragma unroll
    for (int b = 0; b < 4; ++b) {
        int byte = (bytes4 >> (8 * b)) & 0xFF;
        o[2 * b]     = f32_to_bf16((float)((byte & 0xF) - 8) * s);  // low -> even col
        o[2 * b + 1] = f32_to_bf16((float)((byte >> 4) - 8) * s);   // high -> odd col
    }
    uint4 v;
    v.x = (uint32_t)o[0] | ((uint32_t)o[1] << 16);
    v.y = (uint32_t)o[2] | ((uint32_t)o[3] << 16);
    v.z = (uint32_t)o[4] | ((uint32_t)o[5] << 16);
    v.w = (uint32_t)o[6] | ((uint32_t)o[7] << 16);
    ((uint4*)W)[idx] = v;
}

// ---------------------------------------------------------------------------
// Kernel 2: scatter-add COO residual into bf16 W.  CAS loop on the 32-bit
// word holding two bf16s (duplicate (r,c) triplets -> atomicity required).
// Handles ortho_vals delivered as fp16 OR widened to fp32:
//   fp32 mode: first 64 f32 reads are ~1e-2 magnitude (|v| in [1e-4,1))
//   fp16 mode: f32 reinterpretation of half pairs gives |v| ~ 1e-19
// ---------------------------------------------------------------------------
__global__ __launch_bounds__(256) void scatter_kernel(
        const void* __restrict__ vals,
        const int*  __restrict__ rows,
        const int*  __restrict__ cols,
        const float* __restrict__ alpha,
        uint16_t*   __restrict__ W,
        int nnz) {
    const int lane = threadIdx.x & 63;
    float p = fabsf(((const float*)vals)[lane]);
    int cnt = __popcll(__ballot(p > 1e-4f && p < 1.0f));
    const bool f32mode = (cnt >= 32);

    int i = blockIdx.x * 256 + threadIdx.x;
    if (i >= nnz) return;
    float v = f32mode ? ((const float*)vals)[i]
                      : __half2float(((const __half*)vals)[i]);
    v *= alpha[0];
    int r = rows[i], c = cols[i];
    uint32_t* word = (uint32_t*)W + (((size_t)r * I_FEAT + c) >> 1);
    bool hi = (c & 1);
    uint32_t old = *word, assumed;
    do {
        assumed = old;
        uint16_t cur = hi ? (uint16_t)(assumed >> 16) : (uint16_t)(assumed & 0xFFFF);
        uint16_t nw  = f32_to_bf16(bf16_to_f32(cur) + v);
        uint32_t neww = hi ? ((assumed & 0x0000FFFFu) | ((uint32_t)nw << 16))
                           : ((assumed & 0xFFFF0000u) | (uint32_t)nw);
        old = atomicCAS(word, assumed, neww);
    } while (old != assumed);
}

// ---------------------------------------------------------------------------
// Kernel 3: x fp32 -> bf16.  One thread per 8 floats.
// ---------------------------------------------------------------------------
__global__ __launch_bounds__(256) void xconv_kernel(
        const float* __restrict__ x,
        uint16_t*    __restrict__ xb) {
    int idx = blockIdx.x * 256 + threadIdx.x;       // 1,048,576 threads
    float4 v0 = ((const float4*)x)[2 * idx];
    float4 v1 = ((const float4*)x)[2 * idx + 1];
    uint4 o;
    o.x = (uint32_t)f32_to_bf16(v0.x) | ((uint32_t)f32_to_bf16(v0.y) << 16);
    o.y = (uint32_t)f32_to_bf16(v0.z) | ((uint32_t)f32_to_bf16(v0.w) << 16);
    o.z = (uint32_t)f32_to_bf16(v1.x) | ((uint32_t)f32_to_bf16(v1.y) << 16);
    o.w = (uint32_t)f32_to_bf16(v1.z) | ((uint32_t)f32_to_bf16(v1.w) << 16);
    ((uint4*)xb)[idx] = o;
}

// ---------------------------------------------------------------------------
// Kernel 4: C[M,N] = A[M,K] * B[N,K]^T  (bf16 in, fp32 out).
// 128x128 tile, BK=32, 2x2 waves of 64x64, 16x16x32 MFMA.
// This round: PLAIN staging (vector global load -> ds_write_b128), no
// global_load_lds — de-risking the async path while inputs are validated.
// ---------------------------------------------------------------------------
__global__ __launch_bounds__(256, 2) void gemm_bt_kernel(
        const uint16_t* __restrict__ A,   // [2048][4096] bf16
        const uint16_t* __restrict__ B,   // [4096][4096] bf16 (row-major [N][K])
        float* __restrict__ C) {          // [2048][4096] fp32
    __shared__ uint16_t As[128 * 32];
    __shared__ uint16_t Bs[128 * 32];

    const int tid  = threadIdx.x;
    const int wave = tid >> 6;
    const int lane = tid & 63;
    const int wm = wave >> 1, wn = wave & 1;           // 2x2 wave grid
    const int bm0 = blockIdx.y * 128;
    const int bn0 = blockIdx.x * 128;

    floatx4 acc[4][4];
#pragma unroll
    for (int i = 0; i < 4; ++i)
#pragma unroll
        for (int j = 0; j < 4; ++j) acc[i][j] = {0.f, 0.f, 0.f, 0.f};

    const int fr = lane & 15;            // fragment row within 16
    const int ko = (lane >> 4) * 8;      // fragment k offset

    for (int k0 = 0; k0 < K_DIM; k0 += 32) {
        // stage 128 rows x 32 cols for A and B: 512 uint4 each, 2 per thread
        uint4 areg[2], breg[2];
#pragma unroll
        for (int p = 0; p < 2; ++p) {
            const int li  = p * 256 + tid;           // 0..511
            const int row = li >> 2;                 // 0..127
            const int cs  = (li & 3) * 8;            // 0,8,16,24
            areg[p] = *(const uint4*)&A[(size_t)(bm0 + row) * K_DIM + k0 + cs];
            breg[p] = *(const uint4*)&B[(size_t)(bn0 + row) * K_DIM + k0 + cs];
        }
        __syncthreads();                 // prior LDS reads done before overwrite
#pragma unroll
        for (int p = 0; p < 2; ++p) {
            const int li  = p * 256 + tid;
            const int row = li >> 2;
            const int cs  = (li & 3) * 8;
            *(uint4*)&As[row * 32 + cs] = areg[p];
            *(uint4*)&Bs[row * 32 + cs] = breg[p];
        }
        __syncthreads();

        short8 af[4], bf[4];
#pragma unroll
        for (int i = 0; i < 4; ++i) {
            af[i] = *(const short8*)&As[(wm * 64 + i * 16 + fr) * 32 + ko];
            bf[i] = *(const short8*)&Bs[(wn * 64 + i * 16 + fr) * 32 + ko];
        }
#pragma unroll
        for (int i = 0; i < 4; ++i)
#pragma unroll
            for (int j = 0; j < 4; ++j)
                acc[i][j] = __builtin_amdgcn_mfma_f32_16x16x32_bf16(
                    af[i], bf[j], acc[i][j], 0, 0, 0);
    }

    // epilogue: C/D layout col=lane&15, row=(lane>>4)*4+reg   [m89/m91]
    const int cn = lane & 15;
    const int rb = (lane >> 4) * 4;
#pragma unroll
    for (int i = 0; i < 4; ++i)
#pragma unroll
        for (int j = 0; j < 4; ++j)
#pragma unroll
            for (int r = 0; r < 4; ++r) {
                const int row = bm0 + wm * 64 + i * 16 + rb + r;
                const int col = bn0 + wn * 64 + j * 16 + cn;
                C[(size_t)row * O_FEAT + col] = acc[i][j][r];
            }
}

// ---------------------------------------------------------------------------
extern "C" void kernel_launch(void* const* d_in, const int* in_sizes, int n_in,
                              void* d_out, int out_size, void* d_ws, size_t ws_size,
                              hipStream_t stream) {
    const float* x      = (const float*)d_in[0];
    const void*  packed = d_in[1];
    const float* scales = (const float*)d_in[2];
    const void*  vals   = d_in[3];
    const int*   rows   = (const int*)d_in[4];
    const int*   cols   = (const int*)d_in[5];
    const float* alpha  = (const float*)d_in[6];
    float*       out    = (float*)d_out;
    const int nnz = in_sizes[3];

    uint16_t* W  = (uint16_t*)d_ws;                                        // 32 MB
    uint16_t* Xb = (uint16_t*)((char*)d_ws + (size_t)O_FEAT * I_FEAT * 2); // 16 MB

    dequant_kernel<<<8192, 256, 0, stream>>>(packed, scales, W);
    scatter_kernel<<<(nnz + 255) / 256, 256, 0, stream>>>(vals, rows, cols, alpha, W, nnz);
    xconv_kernel<<<4096, 256, 0, stream>>>(x, Xb);
    gemm_bt_kernel<<<dim3(O_FEAT / 128, M_DIM / 128), 256, 0, stream>>>(Xb, W, out);
}